// Round 1
// 6206.365 us; speedup vs baseline: 1.2788x; 1.2788x over previous
//
#include <hip/hip_runtime.h>

#define TT 1024
#define BB 32
#define HH 512

typedef __attribute__((ext_vector_type(8))) __bf16 bf16x8;
typedef __attribute__((ext_vector_type(8))) short short8;
typedef __attribute__((ext_vector_type(4))) float f32x4;

union frag_u { short8 s; bf16x8 b; f32x4 f; unsigned long long q[2]; };

__device__ __forceinline__ unsigned short f2bf(float f) {
  unsigned int u = __float_as_uint(f);
  u += 0x7FFFu + ((u >> 16) & 1u);
  return (unsigned short)(u >> 16);
}

__device__ __forceinline__ bf16x8 cvt8(const float* p) {
  frag_u u;
#pragma unroll
  for (int j = 0; j < 8; ++j) u.s[j] = (short)f2bf(p[j]);
  return u.b;
}

__device__ __forceinline__ float sigm(float x) {
  return __builtin_amdgcn_rcpf(1.0f + __expf(-x));
}
__device__ __forceinline__ float tanh_(float x) {
  return 1.0f - 2.0f * __builtin_amdgcn_rcpf(1.0f + __expf(2.0f * x));
}

__device__ __forceinline__ unsigned long long aload(const unsigned long long* p) {
  return __hip_atomic_load(p, __ATOMIC_RELAXED, __HIP_MEMORY_SCOPE_AGENT);
}

// Poll a 32-qword (256B/lane) slice of an h buffer until no sentinel dwords
// (0xFFFFFFFF) remain anywhere in the wave. The successful poll IS the data
// load: no separate flag, no producer-side drain. Every published dword is a
// single atomic 4B store of two packed bf16 values; finite LSTM outputs can
// never encode 0xFFFF bf16 (NaN), so per-dword validation is exact.
__device__ __forceinline__ void poll32(const unsigned long long* q0,
                                       unsigned long long hq[32]) {
  for (int it = 0; it < (1 << 20); ++it) {
#pragma unroll
    for (int kc = 0; kc < 16; ++kc) {
      hq[2 * kc] = aload(q0 + kc * 8);
      hq[2 * kc + 1] = aload(q0 + kc * 8 + 1);
    }
    unsigned int bad = 0u;
#pragma unroll
    for (int j = 0; j < 32; ++j) {
      unsigned int lo = (unsigned int)hq[j];
      unsigned int hi = (unsigned int)(hq[j] >> 32);
      bad |= (lo == 0xFFFFFFFFu) ? 1u : 0u;
      bad |= (hi == 0xFFFFFFFFu) ? 1u : 0u;
    }
    if (__all(bad == 0u)) {
      asm volatile("" ::: "memory");
      return;
    }
  }
}

__global__ void xcvt(const float* __restrict__ x, unsigned short* __restrict__ xbf) {
  size_t i = (size_t)blockIdx.x * blockDim.x + threadIdx.x;  // 8192*256 = n/8 exact
  const f32x4* p = (const f32x4*)x + 2 * i;
  f32x4 a = p[0], b = p[1];
  short8 o;
  o[0] = (short)f2bf(a[0]); o[1] = (short)f2bf(a[1]);
  o[2] = (short)f2bf(a[2]); o[3] = (short)f2bf(a[3]);
  o[4] = (short)f2bf(b[0]); o[5] = (short)f2bf(b[1]);
  o[6] = (short)f2bf(b[2]); o[7] = (short)f2bf(b[3]);
  *((short8*)xbf + i) = o;
}

// Poison both h buffers with the sentinel pattern through the SAME
// agent-scope store path the consumers poll through (no dirty-L2 aliasing).
// Per buffer: (TT+1)*BB*HH*2 bytes = 4,198,400 qwords = 4100 blocks * 1024.
__global__ void hfill(unsigned long long* __restrict__ a,
                      unsigned long long* __restrict__ b) {
  size_t base = (size_t)blockIdx.x * 1024 + threadIdx.x;
#pragma unroll
  for (int k = 0; k < 4; ++k) {
    size_t i = base + (size_t)k * 256;
    __hip_atomic_store(a + i, ~0ull, __ATOMIC_RELAXED, __HIP_MEMORY_SCOPE_AGENT);
    __hip_atomic_store(b + i, ~0ull, __ATOMIC_RELAXED, __HIP_MEMORY_SCOPE_AGENT);
  }
}

__global__ __launch_bounds__(64, 1) void lstm_persistent(
    const float* __restrict__ x,
    const float* __restrict__ wih0, const float* __restrict__ whh0,
    const float* __restrict__ bih0, const float* __restrict__ bhh0,
    const float* __restrict__ wih1, const float* __restrict__ whh1,
    const float* __restrict__ bih1, const float* __restrict__ bhh1,
    const float* __restrict__ h0in, const float* __restrict__ c0in,
    float* __restrict__ out,
    const unsigned short* __restrict__ xbf,  // may be null -> read x fp32 directly
    unsigned short* __restrict__ h0buf,      // [TT+1][BB][HH] bf16, sentinel-poisoned
    unsigned short* __restrict__ h1buf)
{
  const int lane = threadIdx.x;            // 0..63
  const int bid = blockIdx.x;              // 0..255
  const int layer = bid >> 7;
  const int sub = bid & 127;
  const int mhalf = sub & 1;               // batch half
  const int slice = sub >> 1;              // 0..63 -> 8 h-cols each
  const int hc0 = slice << 3;
  const int q = lane >> 4;                 // MFMA quad
  const int c16 = lane & 15;               // MFMA n / m index
  const int cmod = lane & 7;
  const bool owner = (c16 < 8);
  const bool pstore = owner && !(c16 & 1); // packed-pair publisher lanes
  const int mbase = mhalf << 4;

  const float* wih = layer ? wih1 : wih0;
  const float* whh = layer ? whh1 : whh0;
  const float* bih = layer ? bih1 : bih0;
  const float* bhh = layer ? bhh1 : bhh0;

  // gate-column map: acc0 -> {i, f}, acc1 -> {g, o} for h-cols hc0..hc0+7
  const int colN0 = owner ? (hc0 + c16) : (512 + hc0 + c16 - 8);
  const int colN1 = owner ? (1024 + hc0 + c16) : (1536 + hc0 + c16 - 8);

  // ---- persistent weight fragments: [W_ih | W_hh] bf16, 256 VGPRs ----
  bf16x8 w0[32], w1[32];
#pragma unroll
  for (int kc = 0; kc < 32; ++kc) {
    const float* s0;
    const float* s1;
    if (kc < 16) {
      s0 = wih + (size_t)colN0 * HH + kc * 32 + q * 8;
      s1 = wih + (size_t)colN1 * HH + kc * 32 + q * 8;
    } else {
      s0 = whh + (size_t)colN0 * HH + (kc - 16) * 32 + q * 8;
      s1 = whh + (size_t)colN1 * HH + (kc - 16) * 32 + q * 8;
    }
    w0[kc] = cvt8(s0);
    w1[kc] = cvt8(s1);
  }
  const float bias0 = bih[colN0] + bhh[colN0];
  const float bias1 = bih[colN1] + bhh[colN1];

  // ---- initial cell state (pair lanes keep duplicates) ----
  float creg[4];
#pragma unroll
  for (int r = 0; r < 4; ++r) {
    int batch = mbase + q * 4 + r;
    creg[r] = c0in[(size_t)layer * BB * HH + (size_t)batch * HH + hc0 + cmod];
  }

  unsigned short* myH = layer ? h1buf : h0buf;

  // ---- publish h_0 slice (bf16, packed 4B agent-coherent stores) ----
  // The store itself is the ready signal: it overwrites sentinel dwords.
  {
    unsigned short* hp = myH;  // t = 0
#pragma unroll
    for (int r = 0; r < 4; ++r) {
      int batch = mbase + q * 4 + r;
      float hv0 = h0in[(size_t)layer * BB * HH + (size_t)batch * HH + hc0 + cmod];
      unsigned short hb = f2bf(hv0);
      unsigned int partner = (unsigned int)__shfl_xor((int)(unsigned int)hb, 1);
      unsigned int packed = ((unsigned int)hb & 0xffffu) | (partner << 16);
      if (pstore) {
        unsigned int* dst = (unsigned int*)(hp + (size_t)batch * HH + hc0 + cmod);
        __hip_atomic_store(dst, packed, __ATOMIC_RELAXED, __HIP_MEMORY_SCOPE_AGENT);
      }
    }
    asm volatile("" ::: "memory");
  }

  const size_t laneoff = (size_t)(mbase + c16) * HH + q * 8;  // shorts

  for (int t = 1; t <= TT; ++t) {
    f32x4 acc0 = {bias0, bias0, bias0, bias0};
    f32x4 acc1 = {bias1, bias1, bias1, bias1};

    if (layer == 0) {
      // ---- input projection (xbf, L2-cached normal loads), off critical path ----
      if (xbf != nullptr) {
        const unsigned short* ip = xbf + (size_t)(t - 1) * BB * HH + laneoff;
#pragma unroll
        for (int kc = 0; kc < 16; ++kc) {
          bf16x8 a = *(const bf16x8*)(const void*)(ip + kc * 32);
          acc0 = __builtin_amdgcn_mfma_f32_16x16x32_bf16(a, w0[kc], acc0, 0, 0, 0);
          acc1 = __builtin_amdgcn_mfma_f32_16x16x32_bf16(a, w1[kc], acc1, 0, 0, 0);
        }
      } else {
        const float* ip = x + (size_t)(t - 1) * BB * HH + laneoff;
#pragma unroll
        for (int kc = 0; kc < 16; ++kc) {
          bf16x8 a = cvt8(ip + kc * 32);
          acc0 = __builtin_amdgcn_mfma_f32_16x16x32_bf16(a, w0[kc], acc0, 0, 0, 0);
          acc1 = __builtin_amdgcn_mfma_f32_16x16x32_bf16(a, w1[kc], acc1, 0, 0, 0);
        }
      }

      // ---- recurrent part: poll h_{t-1} data directly (flag-free) ----
      unsigned long long hq[32];
      poll32((const unsigned long long*)(myH + (size_t)(t - 1) * BB * HH + laneoff), hq);
#pragma unroll
      for (int kc = 0; kc < 16; ++kc) {
        frag_u u;
        u.q[0] = hq[2 * kc];
        u.q[1] = hq[2 * kc + 1];
        acc0 = __builtin_amdgcn_mfma_f32_16x16x32_bf16(u.b, w0[16 + kc], acc0, 0, 0, 0);
        acc1 = __builtin_amdgcn_mfma_f32_16x16x32_bf16(u.b, w1[16 + kc], acc1, 0, 0, 0);
      }
    } else {
      // layer 1: own h1_{t-1} is typically ready first -> poll it, MFMA it
      // (overlapping with layer-0's step-t publish), then poll h0_t.
      {
        unsigned long long fb[32];
        poll32((const unsigned long long*)(h1buf + (size_t)(t - 1) * BB * HH + laneoff), fb);
#pragma unroll
        for (int kc = 0; kc < 16; ++kc) {
          frag_u u;
          u.q[0] = fb[2 * kc];
          u.q[1] = fb[2 * kc + 1];
          acc0 = __builtin_amdgcn_mfma_f32_16x16x32_bf16(u.b, w0[16 + kc], acc0, 0, 0, 0);
          acc1 = __builtin_amdgcn_mfma_f32_16x16x32_bf16(u.b, w1[16 + kc], acc1, 0, 0, 0);
        }
      }
      {
        unsigned long long fa[32];
        poll32((const unsigned long long*)(h0buf + (size_t)t * BB * HH + laneoff), fa);
#pragma unroll
        for (int kc = 0; kc < 16; ++kc) {
          frag_u u;
          u.q[0] = fa[2 * kc];
          u.q[1] = fa[2 * kc + 1];
          acc0 = __builtin_amdgcn_mfma_f32_16x16x32_bf16(u.b, w0[kc], acc0, 0, 0, 0);
          acc1 = __builtin_amdgcn_mfma_f32_16x16x32_bf16(u.b, w1[kc], acc1, 0, 0, 0);
        }
      }
    }

    // ---- elementwise: pair lanes (l <-> l^8) hold {i,g} / {f,o} ----
    float hv[4];
#pragma unroll
    for (int r = 0; r < 4; ++r) {
      float a0 = acc0[r], a1 = acc1[r];
      float p0 = __shfl_xor(a0, 8);
      float p1 = __shfl_xor(a1, 8);
      float iv = owner ? a0 : p0;
      float fv = owner ? p0 : a0;
      float gv = owner ? a1 : p1;
      float ov = owner ? p1 : a1;
      iv = sigm(iv);
      fv = sigm(fv);
      gv = tanh_(gv);
      ov = sigm(ov);
      float c = fv * creg[r] + iv * gv;
      creg[r] = c;
      hv[r] = ov * tanh_(c);
    }

    // ---- publish h_t slice: packed 4B agent-coherent stores. No drain, no
    // flag: the stores themselves clear the sentinels consumers poll. ----
    {
      unsigned short* hp = myH + (size_t)t * BB * HH;
#pragma unroll
      for (int r = 0; r < 4; ++r) {
        int batch = mbase + q * 4 + r;
        unsigned short hb = f2bf(hv[r]);
        unsigned int partner = (unsigned int)__shfl_xor((int)(unsigned int)hb, 1);
        unsigned int packed = ((unsigned int)hb & 0xffffu) | (partner << 16);
        if (pstore) {
          unsigned int* dst = (unsigned int*)(hp + (size_t)batch * HH + hc0 + cmod);
          __hip_atomic_store(dst, packed, __ATOMIC_RELAXED, __HIP_MEMORY_SCOPE_AGENT);
        }
      }
      asm volatile("" ::: "memory");
    }

    // ---- off-critical-path outputs (normal cached stores) ----
    if (layer) {
      float* op = out + (size_t)(t - 1) * BB * HH;
#pragma unroll
      for (int r = 0; r < 4; ++r) {
        int batch = mbase + q * 4 + r;
        if (owner) op[(size_t)batch * HH + hc0 + cmod] = hv[r];
      }
    }
    if (t == TT) {
      float* hn = out + (size_t)TT * BB * HH + (size_t)layer * BB * HH;
      float* cn = out + (size_t)TT * BB * HH + (size_t)2 * BB * HH + (size_t)layer * BB * HH;
#pragma unroll
      for (int r = 0; r < 4; ++r) {
        int batch = mbase + q * 4 + r;
        if (owner) {
          hn[(size_t)batch * HH + hc0 + cmod] = hv[r];
          cn[(size_t)batch * HH + hc0 + cmod] = creg[r];
        }
      }
    }
  }
}

extern "C" void kernel_launch(void* const* d_in, const int* in_sizes, int n_in,
                              void* d_out, int out_size, void* d_ws, size_t ws_size,
                              hipStream_t stream) {
  (void)in_sizes; (void)n_in; (void)out_size;
  const float* x = (const float*)d_in[0];
  const float* wih0 = (const float*)d_in[1];
  const float* whh0 = (const float*)d_in[2];
  const float* bih0 = (const float*)d_in[3];
  const float* bhh0 = (const float*)d_in[4];
  const float* wih1 = (const float*)d_in[5];
  const float* whh1 = (const float*)d_in[6];
  const float* bih1 = (const float*)d_in[7];
  const float* bhh1 = (const float*)d_in[8];
  const float* h0in = (const float*)d_in[9];
  const float* c0in = (const float*)d_in[10];
  float* out = (float*)d_out;
  char* ws = (char*)d_ws;

  const size_t xbf_bytes = (size_t)TT * BB * HH * 2;
  const size_t hbuf_bytes = (size_t)(TT + 1) * BB * HH * 2;
  size_t off = 4096;
  bool use_xbf = ws_size >= off + xbf_bytes + 2 * hbuf_bytes;
  unsigned short* xbf = use_xbf ? (unsigned short*)(ws + off) : nullptr;
  if (use_xbf) off += xbf_bytes;
  unsigned short* h0b = (unsigned short*)(ws + off);
  unsigned short* h1b = (unsigned short*)(ws + off + hbuf_bytes);

  // Re-poison h buffers each launch (sentinel = 0xFFFF bf16 NaN pattern).
  // (TT+1)*BB*HH/4 = 4,198,400 qwords per buffer = 4100 blocks * 1024.
  hfill<<<dim3(4100), dim3(256), 0, stream>>>(
      (unsigned long long*)h0b, (unsigned long long*)h1b);
  if (use_xbf) xcvt<<<dim3(8192), dim3(256), 0, stream>>>(x, xbf);
  lstm_persistent<<<dim3(256), dim3(64), 0, stream>>>(
      x, wih0, whh0, bih0, bhh0, wih1, whh1, bih1, bhh1, h0in, c0in,
      out, xbf, h0b, h1b);
}